// Round 13
// baseline (86.560 us; speedup 1.0000x reference)
//
#include <hip/hip_runtime.h>

// PZCell exact chunked-scan biquad, LDS-coalesced I/O, barrier-free.
//   y_t = b0 x_t + b1 x_{t-1} + b2 x_{t-2} - a1 y_{t-1} - a2 y_{t-2}
// One wave per row (T=2048): 64 lanes x CHUNK=32.
// Each wave owns a PRIVATE 8KB LDS slice -> no cross-wave sharing -> no
// __syncthreads needed; intra-wave DS ordering (program order + lgkmcnt)
// suffices. Waves stream load->compute->store independently (no convoying).
//  - Coalesced global float4 loads (issued first) -> XOR-swizzled LDS ->
//    per-lane contiguous ds_read_b128 chunks (bank-balanced both orders).
//  - Phase 1: zero-state recurrence per lane, outputs in VGPRs.
//  - Phase 2: wave Kogge-Stone scan of the 2-dim y-state (M = A^32).
//  - Phase 3: homogeneous correction, back through LDS, coalesced store.
// Exact up to fp reassociation.

#define T_LEN   2048
#define B_ROWS  4096
#define CHUNK   32
#define ROWS_PER_BLOCK 4    // 4 waves = 256 threads, 8KB LDS per wave

__global__ __launch_bounds__(256, 4) void pzcell_scan_kernel(
    const float* __restrict__ x,
    const float* __restrict__ gain_ri,
    const float* __restrict__ poles_ri,
    const float* __restrict__ zeros_ri,
    float* __restrict__ out)
{
    __shared__ float lds[ROWS_PER_BLOCK][T_LEN];   // 32 KiB, 8KB per wave

    int lane = threadIdx.x & 63;
    int wv   = threadIdx.x >> 6;
    int row  = blockIdx.x * ROWS_PER_BLOCK + wv;

    // ---- issue the 8 coalesced global loads FIRST (hide under coeff calc) ----
    const float4* xg4 = (const float4*)(x + (size_t)row * T_LEN);
    float4 xreg[8];
#pragma unroll
    for (int j = 0; j < 8; ++j) xreg[j] = xg4[j * 64 + lane];

    // ---- coefficients (uniform; VALU work overlaps the loads above) ----
    float gr = gain_ri[0], gi = gain_ri[1];
    float p1r = poles_ri[0];
    float p2r = poles_ri[2];
    float p1i = poles_ri[1], p2i = poles_ri[3];
    float z1r = zeros_ri[0], z1i = zeros_ri[1];
    float z2r = zeros_ri[2], z2i = zeros_ri[3];

    float a1 = -(p1r + p2r);              // Re(pole_coeffs[1])
    float a2 = p1r * p2r - p1i * p2i;     // Re(pole_coeffs[2])
    float zc1r = -(z1r + z2r), zc1i = -(z1i + z2i);
    float zc2r = z1r * z2r - z1i * z2i;
    float zc2i = z1r * z2i + z1i * z2r;
    float b0 = gr;
    float b1 = gr * zc1r - gi * zc1i;
    float b2 = gr * zc2r - gi * zc2i;

    float4* l4 = (float4*)lds[wv];                 // 512 float4 slots per wave

    // ---- stage to swizzled LDS (wave-private; no barrier) ----
    int swz_g = (lane >> 3) & 7;                   // ((g>>3)&7) for g=j*64+lane
#pragma unroll
    for (int j = 0; j < 8; ++j) {
        int g = j * 64 + lane;
        l4[g ^ swz_g] = xreg[j];
    }

    // ---- per-lane chunk from LDS (slot q=lane*8+k -> q^(lane&7)) ----
    // DS ops issue in program order within the wave; compiler inserts lgkmcnt.
    float4 xv[8];
    int qbase = lane * 8, swz_c = lane & 7;
#pragma unroll
    for (int k = 0; k < 8; ++k) xv[k] = l4[(qbase + k) ^ swz_c];

    // cross-chunk x predecessors: previous lane's last two elements
    float xm1 = __shfl_up(xv[7].w, 1);
    float xm2 = __shfl_up(xv[7].z, 1);
    if (lane == 0) { xm1 = 0.f; xm2 = 0.f; }

    // ---- phase 1: zero-init recurrence, outputs stay in registers ----
    float y[CHUNK];
    float y1 = 0.f, y2 = 0.f;
#pragma unroll
    for (int i = 0; i < 8; ++i) {
        float xi, f, yt;
        xi = xv[i].x;
        f  = b0 * xi + b1 * xm1 + b2 * xm2;
        yt = f - a1 * y1 - a2 * y2;
        y[4 * i + 0] = yt; xm2 = xm1; xm1 = xi; y2 = y1; y1 = yt;

        xi = xv[i].y;
        f  = b0 * xi + b1 * xm1 + b2 * xm2;
        yt = f - a1 * y1 - a2 * y2;
        y[4 * i + 1] = yt; xm2 = xm1; xm1 = xi; y2 = y1; y1 = yt;

        xi = xv[i].z;
        f  = b0 * xi + b1 * xm1 + b2 * xm2;
        yt = f - a1 * y1 - a2 * y2;
        y[4 * i + 2] = yt; xm2 = xm1; xm1 = xi; y2 = y1; y1 = yt;

        xi = xv[i].w;
        f  = b0 * xi + b1 * xm1 + b2 * xm2;
        yt = f - a1 * y1 - a2 * y2;
        y[4 * i + 3] = yt; xm2 = xm1; xm1 = xi; y2 = y1; y1 = yt;
    }

    // ---- phase 2: M = A^32 via 5 squarings; Kogge-Stone over 64 lanes ----
    float m00 = -a1, m01 = -a2, m10 = 1.f, m11 = 0.f;
#pragma unroll
    for (int s = 0; s < 5; ++s) {
        float t00 = m00 * m00 + m01 * m10;
        float t01 = m00 * m01 + m01 * m11;
        float t10 = m10 * m00 + m11 * m10;
        float t11 = m10 * m01 + m11 * m11;
        m00 = t00; m01 = t01; m10 = t10; m11 = t11;
    }

    float v1 = y1, v2 = y2;                 // chunk-final state d = (y_31, y_30)
    float p00 = m00, p01 = m01, p10 = m10, p11 = m11;
#pragma unroll
    for (int k = 1; k < 64; k <<= 1) {
        float u1 = __shfl_up(v1, (unsigned)k);
        float u2 = __shfl_up(v2, (unsigned)k);
        if (lane < k) { u1 = 0.f; u2 = 0.f; }
        v1 += p00 * u1 + p01 * u2;
        v2 += p10 * u1 + p11 * u2;
        float t00 = p00 * p00 + p01 * p10;
        float t01 = p00 * p01 + p01 * p11;
        float t10 = p10 * p00 + p11 * p10;
        float t11 = p10 * p01 + p11 * p11;
        p00 = t00; p01 = t01; p10 = t10; p11 = t11;
    }

    float s1 = __shfl_up(v1, 1);            // exclusive: true initial y-state
    float s2 = __shfl_up(v2, 1);
    if (lane == 0) { s1 = 0.f; s2 = 0.f; }

    // ---- phase 3: correction, write y back to wave-private LDS ----
    // x reads (ds_read above) precede these ds_writes in program order; the
    // LDS unit processes a wave's DS ops in order, so no barrier needed.
    float c1 = s1, c2 = s2;
#pragma unroll
    for (int i = 0; i < 8; ++i) {
        float4 o; float c;
        c = -a1 * c1 - a2 * c2; o.x = y[4 * i + 0] + c; c2 = c1; c1 = c;
        c = -a1 * c1 - a2 * c2; o.y = y[4 * i + 1] + c; c2 = c1; c1 = c;
        c = -a1 * c1 - a2 * c2; o.z = y[4 * i + 2] + c; c2 = c1; c1 = c;
        c = -a1 * c1 - a2 * c2; o.w = y[4 * i + 3] + c; c2 = c1; c1 = c;
        l4[(qbase + i) ^ swz_c] = o;
    }

    // ---- coalesced store (reads own wave's LDS; lgkmcnt orders them) ----
    float4* og4 = (float4*)(out + (size_t)row * T_LEN);
#pragma unroll
    for (int j = 0; j < 8; ++j) {
        int g = j * 64 + lane;
        og4[g] = l4[g ^ swz_g];
    }
}

extern "C" void kernel_launch(void* const* d_in, const int* in_sizes, int n_in,
                              void* d_out, int out_size, void* d_ws, size_t ws_size,
                              hipStream_t stream) {
    const float* x        = (const float*)d_in[0];
    const float* gain_ri  = (const float*)d_in[1];
    const float* poles_ri = (const float*)d_in[2];
    const float* zeros_ri = (const float*)d_in[3];
    float* out = (float*)d_out;

    dim3 block(64 * ROWS_PER_BLOCK);                  // 256
    dim3 grid(B_ROWS / ROWS_PER_BLOCK);               // 1024 blocks, 4096 waves
    hipLaunchKernelGGL(pzcell_scan_kernel, grid, block, 0, stream,
                       x, gain_ri, poles_ri, zeros_ri, out);
}